// Round 9
// baseline (192.429 us; speedup 1.0000x reference)
//
#include <hip/hip_runtime.h>
#include <math.h>

// Problem constants
#define NB   4
#define CCH  256
#define HH   64
#define WW   64
#define GG   8
#define GCH  32
#define PP   9
#define HIN  66
#define WIN  66
#define HWSZ 4096            // H*W
#define NPIX 16384           // N*H*W

// Workspace element counts
#define XP_ELEMS  (NB*HIN*WIN*CCH)      // 4460544  (ushort/bf16)
#define X1_ELEMS  (NPIX*CCH)            // 4194304  (ushort/bf16)
#define AGG_ELEMS (NPIX*CCH)            // 4194304  (ushort/bf16)
#define OFF_ELEMS (NPIX*144)            // float
#define MSK_ELEMS (NPIX*72)             // float

typedef __attribute__((ext_vector_type(8))) short bf16x8;
typedef __attribute__((ext_vector_type(4))) float f32x4;

__device__ __forceinline__ unsigned short f2bf(float f) {
    unsigned int u = __float_as_uint(f);
    unsigned int r = (u + 0x7FFFu + ((u >> 16) & 1u)) >> 16;
    return (unsigned short)r;
}
__device__ __forceinline__ float bf2f(unsigned short s) {
    return __uint_as_float(((unsigned int)s) << 16);
}
__device__ __forceinline__ unsigned int f2bf_pk(float lo, float hi) {
    return (unsigned int)f2bf(lo) | ((unsigned int)f2bf(hi) << 16);
}

// LDS row stride (bf16 elems): 32 k + 8 pad = 80 B (16-B aligned rows)
#define AK 40
#define SDW_STRIDE 258

// ---------------------------------------------------------------------------
// Fused front kernel: blocks [0,512) gemm_in | [512,768) dw+LN+GELU | rest ring
// Shared 35.6 KB arena reused per role.
// ---------------------------------------------------------------------------
__global__ __launch_bounds__(256) void k_front(
    const float* __restrict__ x, const float* __restrict__ w_in,
    const float* __restrict__ b_in, const float* __restrict__ w_dw,
    const float* __restrict__ b_dw, const float* __restrict__ ln_g,
    const float* __restrict__ ln_b, unsigned short* __restrict__ xp,
    unsigned short* __restrict__ x1)
{
    __shared__ __align__(16) char smem[35584];
    const int b = blockIdx.x;
    const int tid = threadIdx.x;

    if (b < 512) {
        // ---------------- role: gemm_in (ping-pong LDS double buffer) -------
        short* AsB = (short*)smem;                               // [2][128*AK]
        short* WsB = (short*)(smem + 2 * 128 * AK * sizeof(short)); // [2][64*AK]

        const int m0  = (b & 127) * 128;
        const int co0 = (b >> 7) * 64;
        const int n   = m0 >> 12;
        const int hw0 = m0 & 4095;

        const int wave = tid >> 6;
        const int lane = tid & 63;
        const int r16  = lane & 15;
        const int quad = lane >> 4;
        const int mw   = wave * 32;

        const float* xa = x + (size_t)n * CCH * HWSZ + hw0;

        f32x4 acc[2][4];
#pragma unroll
        for (int i = 0; i < 2; i++)
#pragma unroll
            for (int j = 0; j < 4; j++) acc[i][j] = (f32x4){0.f, 0.f, 0.f, 0.f};

        float apre[16], wpre[8];

        auto loadT = [&](int k0) {
#pragma unroll
            for (int l = 0; l < 8; l++) {
                int idx = tid + l * 256;
                int m = idx & 127, kp = idx >> 7;
                apre[2 * l + 0] = xa[(size_t)(k0 + 2 * kp) * HWSZ + m];
                apre[2 * l + 1] = xa[(size_t)(k0 + 2 * kp + 1) * HWSZ + m];
            }
#pragma unroll
            for (int l = 0; l < 4; l++) {
                int idx = tid + l * 256;
                int nn = idx & 63, kp = idx >> 6;
                wpre[2 * l + 0] = w_in[(size_t)(k0 + 2 * kp) * CCH + co0 + nn];
                wpre[2 * l + 1] = w_in[(size_t)(k0 + 2 * kp + 1) * CCH + co0 + nn];
            }
        };
        auto storeT = [&](int buf) {
            short* A = AsB + buf * 128 * AK;
            short* W = WsB + buf * 64 * AK;
#pragma unroll
            for (int l = 0; l < 8; l++) {
                int idx = tid + l * 256;
                int m = idx & 127, kp = idx >> 7;
                ((unsigned int*)A)[(m * AK) / 2 + kp] = f2bf_pk(apre[2 * l], apre[2 * l + 1]);
            }
#pragma unroll
            for (int l = 0; l < 4; l++) {
                int idx = tid + l * 256;
                int nn = idx & 63, kp = idx >> 6;
                ((unsigned int*)W)[(nn * AK) / 2 + kp] = f2bf_pk(wpre[2 * l], wpre[2 * l + 1]);
            }
        };

        loadT(0);
        storeT(0);
        __syncthreads();

#pragma unroll
        for (int it = 0; it < 8; it++) {
            int cur = it & 1;
            if (it < 7) loadT((it + 1) * 32);
            const short* A = AsB + cur * 128 * AK;
            const short* W = WsB + cur * 64 * AK;
            bf16x8 a0 = *(const bf16x8*)&A[(mw + r16) * AK + quad * 8];
            bf16x8 a1 = *(const bf16x8*)&A[(mw + 16 + r16) * AK + quad * 8];
#pragma unroll
            for (int nt = 0; nt < 4; nt++) {
                bf16x8 bfr = *(const bf16x8*)&W[(nt * 16 + r16) * AK + quad * 8];
                acc[0][nt] = __builtin_amdgcn_mfma_f32_16x16x32_bf16(a0, bfr, acc[0][nt], 0, 0, 0);
                acc[1][nt] = __builtin_amdgcn_mfma_f32_16x16x32_bf16(a1, bfr, acc[1][nt], 0, 0, 0);
            }
            if (it < 7) {
                storeT(cur ^ 1);
                __syncthreads();
            }
        }

#pragma unroll
        for (int nt = 0; nt < 4; nt++) {
            int co = co0 + nt * 16 + r16;
            float bias = b_in[co];
#pragma unroll
            for (int mt = 0; mt < 2; mt++) {
                int mbase = mw + mt * 16 + quad * 4;
#pragma unroll
                for (int r = 0; r < 4; r++) {
                    int hw = hw0 + mbase + r;
                    int h = hw >> 6, w = hw & 63;
                    xp[(((size_t)n * HIN + (h + 1)) * WIN + (w + 1)) * CCH + co] =
                        f2bf(acc[mt][nt][r] + bias);
                }
            }
        }
    } else if (b < 768) {
        // ---------------- role: depthwise 3x3 + LN + GELU (4 waves) ---------
        unsigned short* sdw = (unsigned short*)smem;            // [64*258]
        float* r1s = (float*)(smem + 33024);                     // [4][64]
        float* r2s = (float*)(smem + 34048);                     // [4][64]
        float* mu_s = (float*)(smem + 35072);                    // [64]
        float* rs_s = (float*)(smem + 35328);                    // [64]

        const int idx = b - 512;
        const int h = idx & 63;
        const int n = idx >> 6;
        const int wave = tid >> 6;        // 0..3
        const int lane = tid & 63;        // = w

        const float* xn = x + (size_t)n * CCH * HWSZ;
        const bool h0ok = (h > 0);
        const bool h2ok = (h < HH - 1);

        float s1 = 0.f, s2 = 0.f;

#pragma unroll 4
        for (int it = 0; it < 64; it++) {
            const int c = it * 4 + wave;
            const float* xc = xn + (size_t)c * HWSZ + h * WW + lane;
            float v0 = h0ok ? xc[-WW] : 0.f;
            float v1 = xc[0];
            float v2 = h2ok ? xc[WW] : 0.f;

            const float* wk = w_dw + c * 9;
            float acc = b_dw[c];

            float l0 = __shfl_up(v0, 1);   if (lane == 0)  l0 = 0.f;
            float r0 = __shfl_down(v0, 1); if (lane == 63) r0 = 0.f;
            acc += wk[0] * l0 + wk[1] * v0 + wk[2] * r0;

            float l1 = __shfl_up(v1, 1);   if (lane == 0)  l1 = 0.f;
            float r1 = __shfl_down(v1, 1); if (lane == 63) r1 = 0.f;
            acc += wk[3] * l1 + wk[4] * v1 + wk[5] * r1;

            float l2 = __shfl_up(v2, 1);   if (lane == 0)  l2 = 0.f;
            float r2 = __shfl_down(v2, 1); if (lane == 63) r2 = 0.f;
            acc += wk[6] * l2 + wk[7] * v2 + wk[8] * r2;

            s1 += acc;
            s2 += acc * acc;
            sdw[lane * SDW_STRIDE + c] = f2bf(acc);
        }

        r1s[wave * 64 + lane] = s1;
        r2s[wave * 64 + lane] = s2;
        __syncthreads();

        if (tid < 64) {
            float a1 = 0.f, a2 = 0.f;
#pragma unroll
            for (int q = 0; q < 4; q++) { a1 += r1s[q * 64 + tid]; a2 += r2s[q * 64 + tid]; }
            float mu = a1 * (1.0f / 256.0f);
            float var = a2 * (1.0f / 256.0f) - mu * mu;
            mu_s[tid] = mu;
            rs_s[tid] = rsqrtf(var + 1e-5f);
        }
        __syncthreads();

        const int c0 = (tid & 63) * 4;
        const int wq = tid >> 6;          // 0..3
        float g4[4], b4[4];
#pragma unroll
        for (int i = 0; i < 4; i++) { g4[i] = ln_g[c0 + i]; b4[i] = ln_b[c0 + i]; }

        unsigned short* x1p = x1 + (((size_t)n * HH + h) * WW) * CCH + c0;
#pragma unroll
        for (int pass = 0; pass < 16; pass++) {
            int w = wq + pass * 4;
            float mu = mu_s[w], rs = rs_s[w];
            const unsigned short* row = &sdw[w * SDW_STRIDE + c0];
            unsigned short tmp[4];
#pragma unroll
            for (int i = 0; i < 4; i++) {
                float v = (bf2f(row[i]) - mu) * rs * g4[i] + b4[i];
                tmp[i] = f2bf(0.5f * v * (1.0f + erff(v * 0.70710678118654752f)));
            }
            ushort4 o; o.x = tmp[0]; o.y = tmp[1]; o.z = tmp[2]; o.w = tmp[3];
            *(ushort4*)&x1p[(size_t)w * CCH] = o;
        }
    } else {
        // ---------------- role: zero pad ring of xp -------------------------
        int gi = (b - 768) * 256 + tid;       // 0..66559
        int seg = gi >> 6, ln = gi & 63;
        int n = seg / 260, rp = seg % 260;
        int h, w;
        if (rp < 66)       { h = 0;        w = rp; }
        else if (rp < 132) { h = 65;       w = rp - 66; }
        else if (rp < 196) { h = rp - 131; w = 0; }
        else               { h = rp - 195; w = 65; }
        uint2 z = make_uint2(0u, 0u);
        *(uint2*)&xp[(((size_t)n * HIN + h) * WIN + w) * CCH + ln * 4] = z;
    }
}

// ---------------------------------------------------------------------------
// Kernel: x1(bf16) @ [w_off|w_mask] + bias -> off, msk (fp32); ping-pong LDS
// ---------------------------------------------------------------------------
__global__ __launch_bounds__(256) void k_gemm_offmask(
    const unsigned short* __restrict__ x1, const float* __restrict__ w_off,
    const float* __restrict__ b_off, const float* __restrict__ w_mask,
    const float* __restrict__ b_mask, float* __restrict__ off,
    float* __restrict__ msk)
{
    __shared__ short As[2 * 128 * AK];
    __shared__ short Ws[2 * 64 * AK];

    const int m0  = blockIdx.x * 128;
    const int co0 = blockIdx.y * 64;       // cols 0..215 valid
    const int tid = threadIdx.x;

    const int wave = tid >> 6;
    const int lane = tid & 63;
    const int r16  = lane & 15;
    const int quad = lane >> 4;
    const int mw   = wave * 32;

    const int am = tid >> 2, akq = tid & 3;
    const int wn = tid & 63, wkp = tid >> 6;

    f32x4 acc[2][4];
#pragma unroll
    for (int i = 0; i < 2; i++)
#pragma unroll
        for (int j = 0; j < 4; j++) acc[i][j] = (f32x4){0.f, 0.f, 0.f, 0.f};

    uint4 apre[2];
    float wpre[8];

    auto loadT = [&](int k0) {
#pragma unroll
        for (int l = 0; l < 2; l++) {
            int m = am + l * 64;
            apre[l] = *(const uint4*)&x1[(size_t)(m0 + m) * CCH + k0 + akq * 8];
        }
#pragma unroll
        for (int l = 0; l < 4; l++) {
            int kp = wkp + l * 4;
            int col = co0 + wn;
            float v0 = 0.f, v1 = 0.f;
            if (col < 144) {
                v0 = w_off[(size_t)(k0 + 2 * kp) * 144 + col];
                v1 = w_off[(size_t)(k0 + 2 * kp + 1) * 144 + col];
            } else if (col < 216) {
                v0 = w_mask[(size_t)(k0 + 2 * kp) * 72 + col - 144];
                v1 = w_mask[(size_t)(k0 + 2 * kp + 1) * 72 + col - 144];
            }
            wpre[2 * l] = v0; wpre[2 * l + 1] = v1;
        }
    };
    auto storeT = [&](int buf) {
        short* A = As + buf * 128 * AK;
        short* W = Ws + buf * 64 * AK;
#pragma unroll
        for (int l = 0; l < 2; l++) {
            int m = am + l * 64;
            *(uint4*)&A[m * AK + akq * 8] = apre[l];
        }
#pragma unroll
        for (int l = 0; l < 4; l++) {
            int kp = wkp + l * 4;
            ((unsigned int*)W)[(wn * AK) / 2 + kp] = f2bf_pk(wpre[2 * l], wpre[2 * l + 1]);
        }
    };

    loadT(0);
    storeT(0);
    __syncthreads();

#pragma unroll
    for (int it = 0; it < 8; it++) {
        int cur = it & 1;
        if (it < 7) loadT((it + 1) * 32);
        const short* A = As + cur * 128 * AK;
        const short* W = Ws + cur * 64 * AK;
        bf16x8 a0 = *(const bf16x8*)&A[(mw + r16) * AK + quad * 8];
        bf16x8 a1 = *(const bf16x8*)&A[(mw + 16 + r16) * AK + quad * 8];
#pragma unroll
        for (int nt = 0; nt < 4; nt++) {
            bf16x8 bfr = *(const bf16x8*)&W[(nt * 16 + r16) * AK + quad * 8];
            acc[0][nt] = __builtin_amdgcn_mfma_f32_16x16x32_bf16(a0, bfr, acc[0][nt], 0, 0, 0);
            acc[1][nt] = __builtin_amdgcn_mfma_f32_16x16x32_bf16(a1, bfr, acc[1][nt], 0, 0, 0);
        }
        if (it < 7) {
            storeT(cur ^ 1);
            __syncthreads();
        }
    }

#pragma unroll
    for (int nt = 0; nt < 4; nt++) {
        int col = co0 + nt * 16 + r16;
        if (col >= 216) continue;
        float bias = (col < 144) ? b_off[col] : b_mask[col - 144];
#pragma unroll
        for (int mt = 0; mt < 2; mt++) {
            int mbase = m0 + mw + mt * 16 + quad * 4;
#pragma unroll
            for (int r = 0; r < 4; r++) {
                int p = mbase + r;
                float v = acc[mt][nt][r] + bias;
                if (col < 144) off[(size_t)p * 144 + col] = v;
                else           msk[(size_t)p * 72 + col - 144] = v;
            }
        }
    }
}

// ---------------------------------------------------------------------------
// Kernel: deformable sampling + aggregation, 8 px/block, 8 ch/lane (uint4)
// ---------------------------------------------------------------------------
__device__ __forceinline__ void acc8_tap(float* a, uint4 vv, float wgt) {
    a[0] += wgt * __uint_as_float(vv.x << 16);
    a[1] += wgt * __uint_as_float(vv.x & 0xffff0000u);
    a[2] += wgt * __uint_as_float(vv.y << 16);
    a[3] += wgt * __uint_as_float(vv.y & 0xffff0000u);
    a[4] += wgt * __uint_as_float(vv.z << 16);
    a[5] += wgt * __uint_as_float(vv.z & 0xffff0000u);
    a[6] += wgt * __uint_as_float(vv.w << 16);
    a[7] += wgt * __uint_as_float(vv.w & 0xffff0000u);
}

__global__ __launch_bounds__(256) void k_sample_agg(
    const unsigned short* __restrict__ xp, const float* __restrict__ off,
    const float* __restrict__ msk, unsigned short* __restrict__ agg)
{
    __shared__ float  sm[576];
    __shared__ int2   tco[576];
    __shared__ float4 twt[576];

    const int tid = threadIdx.x;
    const int s0 = blockIdx.x * 8;

    if (tid < 64) {
        const int pix = tid >> 3, g = tid & 7;
        const float* mskp = msk + (size_t)(s0 + pix) * 72 + g * 9;
        float e[9];
        float mx = -1e30f;
#pragma unroll
        for (int p = 0; p < PP; p++) { e[p] = mskp[p]; mx = fmaxf(mx, e[p]); }
        float sum = 0.f;
#pragma unroll
        for (int p = 0; p < PP; p++) { e[p] = __expf(e[p] - mx); sum += e[p]; }
        float rs = 1.0f / sum;
#pragma unroll
        for (int p = 0; p < PP; p++) sm[tid * 9 + p] = e[p] * rs;
    }
    __syncthreads();

    for (int idx = tid; idx < 576; idx += 256) {
        int pix = idx / 72;
        int rem = idx - pix * 72;
        int g = rem / 9;
        int p = rem - g * 9;
        int s = s0 + pix;
        int hw = s & 4095;
        int h = hw >> 6, w = hw & 63;
        const float* offp = off + (size_t)s * 144 + g * 18 + p * 2;
        float ox = offp[0], oy = offp[1];
        int i = p / 3, j = p - i * 3;
        float fx = (float)(w + i) + ox;
        float fy = (float)(h + j) + oy;
        float x0f = floorf(fx), y0f = floorf(fy);
        int x0 = (int)x0f, y0 = (int)y0f;
        float wx = fx - x0f, wy = fy - y0f;
        float m = sm[idx];
        float w00 = (1.f - wx) * (1.f - wy) * m;
        float w10 = wx * (1.f - wy) * m;
        float w01 = (1.f - wx) * wy * m;
        float w11 = wx * wy * m;
        int x1c = x0 + 1, y1c = y0 + 1;
        if (!((x0  >= 0) && (x0  < WIN))) { w00 = 0.f; w01 = 0.f; }
        if (!((x1c >= 0) && (x1c < WIN))) { w10 = 0.f; w11 = 0.f; }
        if (!((y0  >= 0) && (y0  < HIN))) { w00 = 0.f; w10 = 0.f; }
        if (!((y1c >= 0) && (y1c < HIN))) { w01 = 0.f; w11 = 0.f; }
        int cx0 = min(max(x0, 0), WIN - 1), cx1 = min(max(x1c, 0), WIN - 1);
        int cy0 = min(max(y0, 0), HIN - 1), cy1 = min(max(y1c, 0), HIN - 1);
        tco[idx] = make_int2(cx0 | (cx1 << 16), cy0 | (cy1 << 16));
        twt[idx] = make_float4(w00, w10, w01, w11);
    }
    __syncthreads();

    const int pix = tid >> 5;
    const int l5 = tid & 31;
    const int g = l5 >> 2, c8 = l5 & 3;
    const int s = s0 + pix;
    const int n = s >> 12;
    const unsigned short* base = xp + (size_t)n * HIN * WIN * CCH + g * GCH + c8 * 8;
    const int tbase = pix * 72 + g * 9;

    float a[8];
#pragma unroll
    for (int i = 0; i < 8; i++) a[i] = 0.f;

#pragma unroll
    for (int p = 0; p < PP; p++) {
        int2 cc = tco[tbase + p];
        float4 wt = twt[tbase + p];
        int cx0 = cc.x & 0xFFFF, cx1 = cc.x >> 16;
        int cy0 = cc.y & 0xFFFF, cy1 = cc.y >> 16;
        const unsigned short* r0 = base + (size_t)(cy0 * WIN) * CCH;
        const unsigned short* r1 = base + (size_t)(cy1 * WIN) * CCH;
        uint4 v00 = *(const uint4*)&r0[(size_t)cx0 * CCH];
        uint4 v10 = *(const uint4*)&r0[(size_t)cx1 * CCH];
        uint4 v01 = *(const uint4*)&r1[(size_t)cx0 * CCH];
        uint4 v11 = *(const uint4*)&r1[(size_t)cx1 * CCH];
        acc8_tap(a, v00, wt.x);
        acc8_tap(a, v10, wt.y);
        acc8_tap(a, v01, wt.z);
        acc8_tap(a, v11, wt.w);
    }

    uint4 o;
    o.x = (unsigned int)f2bf(a[0]) | ((unsigned int)f2bf(a[1]) << 16);
    o.y = (unsigned int)f2bf(a[2]) | ((unsigned int)f2bf(a[3]) << 16);
    o.z = (unsigned int)f2bf(a[4]) | ((unsigned int)f2bf(a[5]) << 16);
    o.w = (unsigned int)f2bf(a[6]) | ((unsigned int)f2bf(a[7]) << 16);
    *(uint4*)&agg[(size_t)s * CCH + g * GCH + c8 * 8] = o;
}

// ---------------------------------------------------------------------------
// Kernel: agg(bf16) @ w_out + b_out -> BN -> SiLU -> out (NCHW fp32); ping-pong
// ---------------------------------------------------------------------------
__global__ __launch_bounds__(256) void k_gemm_out(
    const unsigned short* __restrict__ agg, const float* __restrict__ w_out,
    const float* __restrict__ b_out, const float* __restrict__ bn_g,
    const float* __restrict__ bn_b, const float* __restrict__ bn_mean,
    const float* __restrict__ bn_var, float* __restrict__ out)
{
    __shared__ short As[2 * 128 * AK];
    __shared__ short Ws[2 * 64 * AK];

    const int m0  = blockIdx.x * 128;
    const int co0 = blockIdx.y * 64;
    const int tid = threadIdx.x;
    const int n   = m0 >> 12;
    const int hw0 = m0 & 4095;

    const int wave = tid >> 6;
    const int lane = tid & 63;
    const int r16  = lane & 15;
    const int quad = lane >> 4;
    const int mw   = wave * 32;

    const int am = tid >> 2, akq = tid & 3;
    const int wn = tid & 63, wkp = tid >> 6;

    f32x4 acc[2][4];
#pragma unroll
    for (int i = 0; i < 2; i++)
#pragma unroll
        for (int j = 0; j < 4; j++) acc[i][j] = (f32x4){0.f, 0.f, 0.f, 0.f};

    uint4 apre[2];
    float wpre[8];

    auto loadT = [&](int k0) {
#pragma unroll
        for (int l = 0; l < 2; l++) {
            int m = am + l * 64;
            apre[l] = *(const uint4*)&agg[(size_t)(m0 + m) * CCH + k0 + akq * 8];
        }
#pragma unroll
        for (int l = 0; l < 4; l++) {
            int kp = wkp + l * 4;
            wpre[2 * l + 0] = w_out[(size_t)(k0 + 2 * kp) * CCH + co0 + wn];
            wpre[2 * l + 1] = w_out[(size_t)(k0 + 2 * kp + 1) * CCH + co0 + wn];
        }
    };
    auto storeT = [&](int buf) {
        short* A = As + buf * 128 * AK;
        short* W = Ws + buf * 64 * AK;
#pragma unroll
        for (int l = 0; l < 2; l++) {
            int m = am + l * 64;
            *(uint4*)&A[m * AK + akq * 8] = apre[l];
        }
#pragma unroll
        for (int l = 0; l < 4; l++) {
            int kp = wkp + l * 4;
            ((unsigned int*)W)[(wn * AK) / 2 + kp] = f2bf_pk(wpre[2 * l], wpre[2 * l + 1]);
        }
    };

    loadT(0);
    storeT(0);
    __syncthreads();

#pragma unroll
    for (int it = 0; it < 8; it++) {
        int cur = it & 1;
        if (it < 7) loadT((it + 1) * 32);
        const short* A = As + cur * 128 * AK;
        const short* W = Ws + cur * 64 * AK;
        bf16x8 a0 = *(const bf16x8*)&A[(mw + r16) * AK + quad * 8];
        bf16x8 a1 = *(const bf16x8*)&A[(mw + 16 + r16) * AK + quad * 8];
#pragma unroll
        for (int nt = 0; nt < 4; nt++) {
            bf16x8 bfr = *(const bf16x8*)&W[(nt * 16 + r16) * AK + quad * 8];
            acc[0][nt] = __builtin_amdgcn_mfma_f32_16x16x32_bf16(a0, bfr, acc[0][nt], 0, 0, 0);
            acc[1][nt] = __builtin_amdgcn_mfma_f32_16x16x32_bf16(a1, bfr, acc[1][nt], 0, 0, 0);
        }
        if (it < 7) {
            storeT(cur ^ 1);
            __syncthreads();
        }
    }

#pragma unroll
    for (int nt = 0; nt < 4; nt++) {
        int co = co0 + nt * 16 + r16;
        float mean = bn_mean[co];
        float rstd = rsqrtf(bn_var[co] + 1e-5f);
        float gg = bn_g[co], bb = bn_b[co], bo = b_out[co];
#pragma unroll
        for (int mt = 0; mt < 2; mt++) {
            int hwb = hw0 + mw + mt * 16 + quad * 4;
            float tmp[4];
#pragma unroll
            for (int r = 0; r < 4; r++) {
                float y = acc[mt][nt][r] + bo;
                float yh = (y - mean) * rstd * gg + bb;
                tmp[r] = yh / (1.0f + __expf(-yh));
            }
            float4 v = make_float4(tmp[0], tmp[1], tmp[2], tmp[3]);
            *(float4*)&out[((size_t)n * CCH + co) * HWSZ + hwb] = v;
        }
    }
}

// ---------------------------------------------------------------------------
extern "C" void kernel_launch(void* const* d_in, const int* in_sizes, int n_in,
                              void* d_out, int out_size, void* d_ws, size_t ws_size,
                              hipStream_t stream)
{
    const float* x       = (const float*)d_in[0];
    const float* w_in    = (const float*)d_in[1];
    const float* b_in    = (const float*)d_in[2];
    const float* w_dw    = (const float*)d_in[3];
    const float* b_dw    = (const float*)d_in[4];
    const float* ln_g    = (const float*)d_in[5];
    const float* ln_b    = (const float*)d_in[6];
    const float* w_off   = (const float*)d_in[7];
    const float* b_off   = (const float*)d_in[8];
    const float* w_mask  = (const float*)d_in[9];
    const float* b_mask  = (const float*)d_in[10];
    const float* w_out   = (const float*)d_in[11];
    const float* b_out   = (const float*)d_in[12];
    const float* bn_g    = (const float*)d_in[13];
    const float* bn_b    = (const float*)d_in[14];
    const float* bn_mean = (const float*)d_in[15];
    const float* bn_var  = (const float*)d_in[16];
    float* out = (float*)d_out;

    unsigned short* xp  = (unsigned short*)d_ws;
    unsigned short* x1  = xp + XP_ELEMS;
    unsigned short* agg = x1 + X1_ELEMS;
    float* off = (float*)(agg + AGG_ELEMS);
    float* msk = off + OFF_ELEMS;

    k_front<<<dim3(1028), 256, 0, stream>>>(x, w_in, b_in, w_dw, b_dw, ln_g, ln_b, xp, x1);
    k_gemm_offmask<<<dim3(128, 4), 256, 0, stream>>>(x1, w_off, b_off, w_mask, b_mask, off, msk);
    k_sample_agg<<<dim3(2048), 256, 0, stream>>>(xp, off, msk, agg);
    k_gemm_out<<<dim3(128, 4), 256, 0, stream>>>(agg, w_out, b_out, bn_g, bn_b, bn_mean, bn_var, out);
}

// Round 10
// 179.051 us; speedup vs baseline: 1.0747x; 1.0747x over previous
//
#include <hip/hip_runtime.h>
#include <math.h>

// Problem constants
#define NB   4
#define CCH  256
#define HH   64
#define WW   64
#define GG   8
#define GCH  32
#define PP   9
#define HIN  66
#define WIN  66
#define HWSZ 4096            // H*W
#define NPIX 16384           // N*H*W

// Workspace element counts (ushort unless noted)
#define X16_ELEMS  (NPIX*CCH)           // 4194304  x channels-last bf16
#define XP_ELEMS   (NB*HIN*WIN*CCH)     // 4460544
#define X1_ELEMS   (NPIX*CCH)           // 4194304
#define AGG_ELEMS  (NPIX*CCH)           // 4194304
#define WINT_ELEMS (CCH*CCH)            // w_in^T  [n][k]
#define WOUTT_ELEMS (CCH*CCH)           // w_out^T [n][k]
#define WOMT_ELEMS (216*CCH)            // [w_off|w_mask]^T [col][k]
#define OFF_ELEMS  (NPIX*144)           // float
#define MSK_ELEMS  (NPIX*72)            // float

typedef __attribute__((ext_vector_type(8))) short bf16x8;
typedef __attribute__((ext_vector_type(4))) float f32x4;

__device__ __forceinline__ unsigned short f2bf(float f) {
    unsigned int u = __float_as_uint(f);
    unsigned int r = (u + 0x7FFFu + ((u >> 16) & 1u)) >> 16;
    return (unsigned short)r;
}
__device__ __forceinline__ float bf2f(unsigned short s) {
    return __uint_as_float(((unsigned int)s) << 16);
}

#define SDW_STRIDE 258

// ---------------------------------------------------------------------------
// Kernel 1: blocks [0,256): depthwise 3x3 + LN + GELU -> x1 (bf16) AND
//           emit x16 = x channels-last bf16 (A-operand for gemm_in).
//           blocks [256,324): weight transposes + xp ring zero.
// 512 threads.
// ---------------------------------------------------------------------------
__global__ __launch_bounds__(512) void k_dw_prep(
    const float* __restrict__ x, const float* __restrict__ w_dw,
    const float* __restrict__ b_dw, const float* __restrict__ ln_g,
    const float* __restrict__ ln_b, const float* __restrict__ w_in,
    const float* __restrict__ w_off, const float* __restrict__ w_mask,
    const float* __restrict__ w_out, unsigned short* __restrict__ x1,
    unsigned short* __restrict__ x16, unsigned short* __restrict__ win_t,
    unsigned short* __restrict__ womt, unsigned short* __restrict__ wout_t,
    unsigned short* __restrict__ xp)
{
    const int b = blockIdx.x;
    const int tid = threadIdx.x;

    if (b >= 256) {
        // ---- misc role: weight transposes + ring zero ----
        const int gtid = (b - 256) * 512 + tid;
        const int STRIDE = 68 * 512;          // 34816
        for (int i = gtid; i < 252928; i += STRIDE) {
            if (i < 65536) {
                int n = i & 255, k = i >> 8;
                win_t[n * 256 + k] = f2bf(w_in[i]);          // w_in[k][n]
            } else if (i < 131072) {
                int j = i - 65536;
                int n = j & 255, k = j >> 8;
                wout_t[n * 256 + k] = f2bf(w_out[j]);
            } else if (i < 186368) {
                int j = i - 131072;
                int k = j / 216, col = j - k * 216;
                float v = (col < 144) ? w_off[k * 144 + col]
                                      : w_mask[k * 72 + col - 144];
                womt[col * 256 + k] = f2bf(v);
            } else {
                int r = i - 186368;                 // [0, 66560)
                int seg = r >> 6, ln = r & 63;
                int n = seg / 260, rp = seg % 260;
                int h, w;
                if (rp < 66)       { h = 0;        w = rp; }
                else if (rp < 132) { h = 65;       w = rp - 66; }
                else if (rp < 196) { h = rp - 131; w = 0; }
                else               { h = rp - 195; w = 65; }
                uint2 z = make_uint2(0u, 0u);
                *(uint2*)&xp[(((size_t)n * HIN + h) * WIN + w) * CCH + ln * 4] = z;
            }
        }
        return;
    }

    // ---- dw role ----
    __shared__ unsigned short sdw[64 * SDW_STRIDE];   // conv result [w][c]
    __shared__ unsigned short sxr[64 * SDW_STRIDE];   // raw x       [w][c]
    __shared__ float r1s[8][64];
    __shared__ float r2s[8][64];
    __shared__ float mu_s[64];
    __shared__ float rs_s[64];

    const int h = b & 63;
    const int n = b >> 6;
    const int wave = tid >> 6;
    const int lane = tid & 63;        // = w in phase 1

    const float* xn = x + (size_t)n * CCH * HWSZ;
    const bool h0ok = (h > 0);
    const bool h2ok = (h < HH - 1);

    float s1 = 0.f, s2 = 0.f;

#pragma unroll 4
    for (int it = 0; it < 32; it++) {
        const int c = it * 8 + wave;
        const float* xc = xn + (size_t)c * HWSZ + h * WW + lane;
        float v0 = h0ok ? xc[-WW] : 0.f;
        float v1 = xc[0];
        float v2 = h2ok ? xc[WW] : 0.f;

        const float* wk = w_dw + c * 9;
        float acc = b_dw[c];

        float l0 = __shfl_up(v0, 1);   if (lane == 0)  l0 = 0.f;
        float r0 = __shfl_down(v0, 1); if (lane == 63) r0 = 0.f;
        acc += wk[0] * l0 + wk[1] * v0 + wk[2] * r0;

        float l1 = __shfl_up(v1, 1);   if (lane == 0)  l1 = 0.f;
        float r1 = __shfl_down(v1, 1); if (lane == 63) r1 = 0.f;
        acc += wk[3] * l1 + wk[4] * v1 + wk[5] * r1;

        float l2 = __shfl_up(v2, 1);   if (lane == 0)  l2 = 0.f;
        float r2 = __shfl_down(v2, 1); if (lane == 63) r2 = 0.f;
        acc += wk[6] * l2 + wk[7] * v2 + wk[8] * r2;

        s1 += acc;
        s2 += acc * acc;
        sdw[lane * SDW_STRIDE + c] = f2bf(acc);
        sxr[lane * SDW_STRIDE + c] = f2bf(v1);
    }

    r1s[wave][lane] = s1;
    r2s[wave][lane] = s2;
    __syncthreads();

    if (tid < 64) {
        float a1 = 0.f, a2 = 0.f;
#pragma unroll
        for (int q = 0; q < 8; q++) { a1 += r1s[q][tid]; a2 += r2s[q][tid]; }
        float mu = a1 * (1.0f / 256.0f);
        float var = a2 * (1.0f / 256.0f) - mu * mu;
        mu_s[tid] = mu;
        rs_s[tid] = rsqrtf(var + 1e-5f);
    }
    __syncthreads();

    const int c0 = (tid & 63) * 4;
    const int wq = tid >> 6;          // 0..7
    float g4[4], b4[4];
#pragma unroll
    for (int i = 0; i < 4; i++) { g4[i] = ln_g[c0 + i]; b4[i] = ln_b[c0 + i]; }

    unsigned short* x1p  = x1  + (((size_t)n * HH + h) * WW) * CCH + c0;
    unsigned short* x16p = x16 + (((size_t)n * HH + h) * WW) * CCH + c0;
#pragma unroll
    for (int pass = 0; pass < 8; pass++) {
        int w = wq + pass * 8;
        float mu = mu_s[w], rs = rs_s[w];
        const unsigned short* row  = &sdw[w * SDW_STRIDE + c0];
        const unsigned short* rowx = &sxr[w * SDW_STRIDE + c0];
        unsigned short tmp[4];
#pragma unroll
        for (int i = 0; i < 4; i++) {
            float v = (bf2f(row[i]) - mu) * rs * g4[i] + b4[i];
            tmp[i] = f2bf(0.5f * v * (1.0f + erff(v * 0.70710678118654752f)));
        }
        ushort4 o; o.x = tmp[0]; o.y = tmp[1]; o.z = tmp[2]; o.w = tmp[3];
        *(ushort4*)&x1p[(size_t)w * CCH] = o;
        ushort4 xo; xo.x = rowx[0]; xo.y = rowx[1]; xo.z = rowx[2]; xo.w = rowx[3];
        *(ushort4*)&x16p[(size_t)w * CCH] = xo;
    }
}

// ---------------------------------------------------------------------------
// Kernel 2: fused barrier-free GEMMs (no LDS, direct fragment loads from L2)
// blocks [0,512):   gemm_in  : x16 @ win_t^T  (+bias) -> xp (bf16 padded)
// blocks [512,1024): offmask : x1 @ womt^T (+bias) -> off, msk (fp32)
// ---------------------------------------------------------------------------
__global__ __launch_bounds__(256) void k_proj(
    const unsigned short* __restrict__ x16, const unsigned short* __restrict__ win_t,
    const float* __restrict__ b_in, unsigned short* __restrict__ xp,
    const unsigned short* __restrict__ x1, const unsigned short* __restrict__ womt,
    const float* __restrict__ b_off, const float* __restrict__ b_mask,
    float* __restrict__ off, float* __restrict__ msk)
{
    const int b = blockIdx.x;
    const int tid = threadIdx.x;
    const int wave = tid >> 6;
    const int lane = tid & 63;
    const int r16  = lane & 15;
    const int quad = lane >> 4;
    const int mw   = wave * 32;

    f32x4 acc[2][4];
#pragma unroll
    for (int i = 0; i < 2; i++)
#pragma unroll
        for (int j = 0; j < 4; j++) acc[i][j] = (f32x4){0.f, 0.f, 0.f, 0.f};

    if (b < 512) {
        // ---- gemm_in role ----
        const int m0  = (b & 127) * 128;
        const int co0 = (b >> 7) * 64;
        const int n   = m0 >> 12;
        const int hw0 = m0 & 4095;

        const unsigned short* a0p = x16 + (size_t)(m0 + mw + r16) * CCH + quad * 8;
        const unsigned short* a1p = a0p + 16 * CCH;

#pragma unroll
        for (int k0 = 0; k0 < CCH; k0 += 32) {
            bf16x8 a0 = *(const bf16x8*)&a0p[k0];
            bf16x8 a1 = *(const bf16x8*)&a1p[k0];
#pragma unroll
            for (int nt = 0; nt < 4; nt++) {
                bf16x8 bfr = *(const bf16x8*)&win_t[(size_t)(co0 + nt * 16 + r16) * CCH + k0 + quad * 8];
                acc[0][nt] = __builtin_amdgcn_mfma_f32_16x16x32_bf16(a0, bfr, acc[0][nt], 0, 0, 0);
                acc[1][nt] = __builtin_amdgcn_mfma_f32_16x16x32_bf16(a1, bfr, acc[1][nt], 0, 0, 0);
            }
        }

#pragma unroll
        for (int nt = 0; nt < 4; nt++) {
            int co = co0 + nt * 16 + r16;
            float bias = b_in[co];
#pragma unroll
            for (int mt = 0; mt < 2; mt++) {
                int mbase = mw + mt * 16 + quad * 4;
#pragma unroll
                for (int r = 0; r < 4; r++) {
                    int hw = hw0 + mbase + r;
                    int h = hw >> 6, w = hw & 63;
                    xp[(((size_t)n * HIN + (h + 1)) * WIN + (w + 1)) * CCH + co] =
                        f2bf(acc[mt][nt][r] + bias);
                }
            }
        }
    } else {
        // ---- offmask role ----
        const int b2 = b - 512;
        const int m0  = (b2 & 127) * 128;
        const int co0 = (b2 >> 7) * 64;       // 0..192; cols 0..215 valid

        const unsigned short* a0p = x1 + (size_t)(m0 + mw + r16) * CCH + quad * 8;
        const unsigned short* a1p = a0p + 16 * CCH;

#pragma unroll
        for (int k0 = 0; k0 < CCH; k0 += 32) {
            bf16x8 a0 = *(const bf16x8*)&a0p[k0];
            bf16x8 a1 = *(const bf16x8*)&a1p[k0];
#pragma unroll
            for (int nt = 0; nt < 4; nt++) {
                int col = co0 + nt * 16 + r16;
                int colc = (col < 216) ? col : 215;      // clamp: safe addr, result discarded
                bf16x8 bfr = *(const bf16x8*)&womt[(size_t)colc * CCH + k0 + quad * 8];
                acc[0][nt] = __builtin_amdgcn_mfma_f32_16x16x32_bf16(a0, bfr, acc[0][nt], 0, 0, 0);
                acc[1][nt] = __builtin_amdgcn_mfma_f32_16x16x32_bf16(a1, bfr, acc[1][nt], 0, 0, 0);
            }
        }

#pragma unroll
        for (int nt = 0; nt < 4; nt++) {
            int col = co0 + nt * 16 + r16;
            if (col >= 216) continue;
            float bias = (col < 144) ? b_off[col] : b_mask[col - 144];
#pragma unroll
            for (int mt = 0; mt < 2; mt++) {
                int mbase = m0 + mw + mt * 16 + quad * 4;
#pragma unroll
                for (int r = 0; r < 4; r++) {
                    int p = mbase + r;
                    float v = acc[mt][nt][r] + bias;
                    if (col < 144) off[(size_t)p * 144 + col] = v;
                    else           msk[(size_t)p * 72 + col - 144] = v;
                }
            }
        }
    }
}

// ---------------------------------------------------------------------------
// Kernel 3: deformable sampling + aggregation, 8 px/block, 8 ch/lane (uint4)
// ---------------------------------------------------------------------------
__device__ __forceinline__ void acc8_tap(float* a, uint4 vv, float wgt) {
    a[0] += wgt * __uint_as_float(vv.x << 16);
    a[1] += wgt * __uint_as_float(vv.x & 0xffff0000u);
    a[2] += wgt * __uint_as_float(vv.y << 16);
    a[3] += wgt * __uint_as_float(vv.y & 0xffff0000u);
    a[4] += wgt * __uint_as_float(vv.z << 16);
    a[5] += wgt * __uint_as_float(vv.z & 0xffff0000u);
    a[6] += wgt * __uint_as_float(vv.w << 16);
    a[7] += wgt * __uint_as_float(vv.w & 0xffff0000u);
}

__global__ __launch_bounds__(256) void k_sample_agg(
    const unsigned short* __restrict__ xp, const float* __restrict__ off,
    const float* __restrict__ msk, unsigned short* __restrict__ agg)
{
    __shared__ float  sm[576];
    __shared__ int2   tco[576];
    __shared__ float4 twt[576];

    const int tid = threadIdx.x;
    const int s0 = blockIdx.x * 8;

    if (tid < 64) {
        const int pix = tid >> 3, g = tid & 7;
        const float* mskp = msk + (size_t)(s0 + pix) * 72 + g * 9;
        float e[9];
        float mx = -1e30f;
#pragma unroll
        for (int p = 0; p < PP; p++) { e[p] = mskp[p]; mx = fmaxf(mx, e[p]); }
        float sum = 0.f;
#pragma unroll
        for (int p = 0; p < PP; p++) { e[p] = __expf(e[p] - mx); sum += e[p]; }
        float rs = 1.0f / sum;
#pragma unroll
        for (int p = 0; p < PP; p++) sm[tid * 9 + p] = e[p] * rs;
    }
    __syncthreads();

    for (int idx = tid; idx < 576; idx += 256) {
        int pix = idx / 72;
        int rem = idx - pix * 72;
        int g = rem / 9;
        int p = rem - g * 9;
        int s = s0 + pix;
        int hw = s & 4095;
        int h = hw >> 6, w = hw & 63;
        const float* offp = off + (size_t)s * 144 + g * 18 + p * 2;
        float ox = offp[0], oy = offp[1];
        int i = p / 3, j = p - i * 3;
        float fx = (float)(w + i) + ox;
        float fy = (float)(h + j) + oy;
        float x0f = floorf(fx), y0f = floorf(fy);
        int x0 = (int)x0f, y0 = (int)y0f;
        float wx = fx - x0f, wy = fy - y0f;
        float m = sm[idx];
        float w00 = (1.f - wx) * (1.f - wy) * m;
        float w10 = wx * (1.f - wy) * m;
        float w01 = (1.f - wx) * wy * m;
        float w11 = wx * wy * m;
        int x1c = x0 + 1, y1c = y0 + 1;
        if (!((x0  >= 0) && (x0  < WIN))) { w00 = 0.f; w01 = 0.f; }
        if (!((x1c >= 0) && (x1c < WIN))) { w10 = 0.f; w11 = 0.f; }
        if (!((y0  >= 0) && (y0  < HIN))) { w00 = 0.f; w10 = 0.f; }
        if (!((y1c >= 0) && (y1c < HIN))) { w01 = 0.f; w11 = 0.f; }
        int cx0 = min(max(x0, 0), WIN - 1), cx1 = min(max(x1c, 0), WIN - 1);
        int cy0 = min(max(y0, 0), HIN - 1), cy1 = min(max(y1c, 0), HIN - 1);
        tco[idx] = make_int2(cx0 | (cx1 << 16), cy0 | (cy1 << 16));
        twt[idx] = make_float4(w00, w10, w01, w11);
    }
    __syncthreads();

    const int pix = tid >> 5;
    const int l5 = tid & 31;
    const int g = l5 >> 2, c8 = l5 & 3;
    const int s = s0 + pix;
    const int n = s >> 12;
    const unsigned short* base = xp + (size_t)n * HIN * WIN * CCH + g * GCH + c8 * 8;
    const int tbase = pix * 72 + g * 9;

    float a[8];
#pragma unroll
    for (int i = 0; i < 8; i++) a[i] = 0.f;

#pragma unroll
    for (int p = 0; p < PP; p++) {
        int2 cc = tco[tbase + p];
        float4 wt = twt[tbase + p];
        int cx0 = cc.x & 0xFFFF, cx1 = cc.x >> 16;
        int cy0 = cc.y & 0xFFFF, cy1 = cc.y >> 16;
        const unsigned short* r0 = base + (size_t)(cy0 * WIN) * CCH;
        const unsigned short* r1 = base + (size_t)(cy1 * WIN) * CCH;
        uint4 v00 = *(const uint4*)&r0[(size_t)cx0 * CCH];
        uint4 v10 = *(const uint4*)&r0[(size_t)cx1 * CCH];
        uint4 v01 = *(const uint4*)&r1[(size_t)cx0 * CCH];
        uint4 v11 = *(const uint4*)&r1[(size_t)cx1 * CCH];
        acc8_tap(a, v00, wt.x);
        acc8_tap(a, v10, wt.y);
        acc8_tap(a, v01, wt.z);
        acc8_tap(a, v11, wt.w);
    }

    uint4 o;
    o.x = (unsigned int)f2bf(a[0]) | ((unsigned int)f2bf(a[1]) << 16);
    o.y = (unsigned int)f2bf(a[2]) | ((unsigned int)f2bf(a[3]) << 16);
    o.z = (unsigned int)f2bf(a[4]) | ((unsigned int)f2bf(a[5]) << 16);
    o.w = (unsigned int)f2bf(a[6]) | ((unsigned int)f2bf(a[7]) << 16);
    *(uint4*)&agg[(size_t)s * CCH + g * GCH + c8 * 8] = o;
}

// ---------------------------------------------------------------------------
// Kernel 4: agg(bf16) @ wout_t^T + b_out -> BN -> SiLU -> out (NCHW fp32)
// barrier-free direct-load
// ---------------------------------------------------------------------------
__global__ __launch_bounds__(256) void k_gemm_out(
    const unsigned short* __restrict__ agg, const unsigned short* __restrict__ wout_t,
    const float* __restrict__ b_out, const float* __restrict__ bn_g,
    const float* __restrict__ bn_b, const float* __restrict__ bn_mean,
    const float* __restrict__ bn_var, float* __restrict__ out)
{
    const int m0  = blockIdx.x * 128;
    const int co0 = blockIdx.y * 64;
    const int tid = threadIdx.x;
    const int n   = m0 >> 12;
    const int hw0 = m0 & 4095;

    const int wave = tid >> 6;
    const int lane = tid & 63;
    const int r16  = lane & 15;
    const int quad = lane >> 4;
    const int mw   = wave * 32;

    f32x4 acc[2][4];
#pragma unroll
    for (int i = 0; i < 2; i++)
#pragma unroll
        for (int j = 0; j < 4; j++) acc[i][j] = (f32x4){0.f, 0.f, 0.f, 0.f};

    const unsigned short* a0p = agg + (size_t)(m0 + mw + r16) * CCH + quad * 8;
    const unsigned short* a1p = a0p + 16 * CCH;

#pragma unroll
    for (int k0 = 0; k0 < CCH; k0 += 32) {
        bf16x8 a0 = *(const bf16x8*)&a0p[k0];
        bf16x8 a1 = *(const bf16x8*)&a1p[k0];
#pragma unroll
        for (int nt = 0; nt < 4; nt++) {
            bf16x8 bfr = *(const bf16x8*)&wout_t[(size_t)(co0 + nt * 16 + r16) * CCH + k0 + quad * 8];
            acc[0][nt] = __builtin_amdgcn_mfma_f32_16x16x32_bf16(a0, bfr, acc[0][nt], 0, 0, 0);
            acc[1][nt] = __builtin_amdgcn_mfma_f32_16x16x32_bf16(a1, bfr, acc[1][nt], 0, 0, 0);
        }
    }

#pragma unroll
    for (int nt = 0; nt < 4; nt++) {
        int co = co0 + nt * 16 + r16;
        float mean = bn_mean[co];
        float rstd = rsqrtf(bn_var[co] + 1e-5f);
        float gg = bn_g[co], bb = bn_b[co], bo = b_out[co];
#pragma unroll
        for (int mt = 0; mt < 2; mt++) {
            int hwb = hw0 + mw + mt * 16 + quad * 4;
            float tmp[4];
#pragma unroll
            for (int r = 0; r < 4; r++) {
                float y = acc[mt][nt][r] + bo;
                float yh = (y - mean) * rstd * gg + bb;
                tmp[r] = yh / (1.0f + __expf(-yh));
            }
            float4 v = make_float4(tmp[0], tmp[1], tmp[2], tmp[3]);
            *(float4*)&out[((size_t)n * CCH + co) * HWSZ + hwb] = v;
        }
    }
}

// ---------------------------------------------------------------------------
extern "C" void kernel_launch(void* const* d_in, const int* in_sizes, int n_in,
                              void* d_out, int out_size, void* d_ws, size_t ws_size,
                              hipStream_t stream)
{
    const float* x       = (const float*)d_in[0];
    const float* w_in    = (const float*)d_in[1];
    const float* b_in    = (const float*)d_in[2];
    const float* w_dw    = (const float*)d_in[3];
    const float* b_dw    = (const float*)d_in[4];
    const float* ln_g    = (const float*)d_in[5];
    const float* ln_b    = (const float*)d_in[6];
    const float* w_off   = (const float*)d_in[7];
    const float* b_off   = (const float*)d_in[8];
    const float* w_mask  = (const float*)d_in[9];
    const float* b_mask  = (const float*)d_in[10];
    const float* w_out   = (const float*)d_in[11];
    const float* b_out   = (const float*)d_in[12];
    const float* bn_g    = (const float*)d_in[13];
    const float* bn_b    = (const float*)d_in[14];
    const float* bn_mean = (const float*)d_in[15];
    const float* bn_var  = (const float*)d_in[16];
    float* out = (float*)d_out;

    unsigned short* xp     = (unsigned short*)d_ws;
    unsigned short* x16    = xp + XP_ELEMS;
    unsigned short* x1     = x16 + X16_ELEMS;
    unsigned short* agg    = x1 + X1_ELEMS;
    unsigned short* win_t  = agg + AGG_ELEMS;
    unsigned short* wout_t = win_t + WINT_ELEMS;
    unsigned short* womt   = wout_t + WOUTT_ELEMS;
    float* off = (float*)(womt + WOMT_ELEMS);
    float* msk = off + OFF_ELEMS;
    // total ~48.8 MB

    k_dw_prep<<<dim3(324), 512, 0, stream>>>(x, w_dw, b_dw, ln_g, ln_b,
                                             w_in, w_off, w_mask, w_out,
                                             x1, x16, win_t, womt, wout_t, xp);
    k_proj<<<dim3(1024), 256, 0, stream>>>(x16, win_t, b_in, xp,
                                           x1, womt, b_off, b_mask, off, msk);
    k_sample_agg<<<dim3(2048), 256, 0, stream>>>(xp, off, msk, agg);
    k_gemm_out<<<dim3(128, 4), 256, 0, stream>>>(agg, wout_t, b_out, bn_g, bn_b, bn_mean, bn_var, out);
}